// Round 7
// baseline (138.127 us; speedup 1.0000x reference)
//
#include <hip/hip_runtime.h>
#include <hip/hip_bf16.h>

typedef __attribute__((ext_vector_type(8))) short bf16x8;
typedef __attribute__((ext_vector_type(4))) float f32x4;

#define NB 16
#define CD 256
#define HD 64
#define WD 64
#define WP 68   // padded width
#define SD 4096
#define KU 1280  // 5 * 256

__device__ __forceinline__ void gload16(const void* g, void* lds) {
  __builtin_amdgcn_global_load_lds(
      (const __attribute__((address_space(1))) unsigned int*)g,
      (__attribute__((address_space(3))) unsigned int*)lds, 16, 0, 0);
}

// ---------------- prep W3: A[o][j*256+c] = p3[o,c,0,j] (bf16) ----------------
__global__ __launch_bounds__(256) void prep_w3(const float* __restrict__ p3,
                                               __hip_bfloat16* __restrict__ A) {
  int id = blockIdx.x * 256 + threadIdx.x;
  if (id >= CD * KU) return;
  int o = id / KU;
  int r = id - o * KU;
  int j = r >> 8;
  int c = r & 255;
  A[id] = __float2bfloat16(p3[(o * CD + c) * 5 + j]);
}

// ---------------- prep X: t2p [N][H][WP][C] (zero-padded), t5T [N][S][C], t6 [N][C][S] ---
__global__ __launch_bounds__(256) void prep_x(const float* __restrict__ x,
                                              const float* __restrict__ p2,
                                              const float* __restrict__ p4,
                                              const float* __restrict__ p6,
                                              __hip_bfloat16* __restrict__ t2p,
                                              __hip_bfloat16* __restrict__ t5T,
                                              __hip_bfloat16* __restrict__ t6) {
  int h = blockIdx.x;
  int c0 = blockIdx.y * 64;
  int n = blockIdx.z;
  __shared__ float xl[64][67];
  __shared__ float p2l[64];
  __shared__ float wtl[64][8];
  int t = threadIdx.x;

  if (t < 64) p2l[t] = p2[(c0 + t) * HD + h];
  for (int idx = t; idx < 448; idx += 256) {
    int c = idx / 7, k = idx - c * 7;
    wtl[c][k] = p4[(c0 + c) * 7 + k] * p6[k];
  }

  {
    int cq = t >> 4;
    int w4 = (t & 15) * 4;
#pragma unroll
    for (int cc = 0; cc < 4; ++cc) {
      int cl = cc * 16 + cq;
      const float4 xv = *reinterpret_cast<const float4*>(
          &x[(((size_t)n * CD + c0 + cl) * HD + h) * WD + w4]);
      xl[cl][w4 + 0] = xv.x;
      xl[cl][w4 + 1] = xv.y;
      xl[cl][w4 + 2] = xv.z;
      xl[cl][w4 + 3] = xv.w;
    }
  }
  __syncthreads();

  __hip_bfloat16* t2pn = t2p + (size_t)n * HD * WP * CD;
#pragma unroll
  for (int ii = 0; ii < 2; ++ii) {
    int w = (t >> 3) + ii * 32;
    int cb = (t & 7) * 8;
    __hip_bfloat16 o2[8], o5[8];
#pragma unroll
    for (int j = 0; j < 8; ++j) {
      float xv = xl[cb + j][w];
      o5[j] = __float2bfloat16(fmaxf(xv, 0.f));
      o2[j] = __float2bfloat16(p2l[cb + j] * xv);
    }
    size_t s = (size_t)h * 64 + w;
    *reinterpret_cast<bf16x8*>(&t5T[((size_t)n * SD + s) * CD + c0 + cb]) =
        *reinterpret_cast<const bf16x8*>(o5);
    *reinterpret_cast<bf16x8*>(&t2pn[((size_t)h * WP + w + 2) * CD + c0 + cb]) =
        *reinterpret_cast<const bf16x8*>(o2);
  }
  if (t < 32) {
    int pi = t >> 3;
    int wp = (pi < 2) ? pi : pi + 64;
    int cb = (t & 7) * 8;
    bf16x8 z = (bf16x8){0, 0, 0, 0, 0, 0, 0, 0};
    *reinterpret_cast<bf16x8*>(&t2pn[((size_t)h * WP + wp) * CD + c0 + cb]) = z;
  }

#pragma unroll
  for (int ii = 0; ii < 2; ++ii) {
    int cl = (t >> 3) + ii * 32;
    int w8 = (t & 7) * 8;
    float hx[14];
#pragma unroll
    for (int m = 0; m < 14; ++m) {
      int wi = w8 - 3 + m;
      hx[m] = (wi >= 0 && wi < 64) ? xl[cl][wi] : 0.f;
    }
    float wt[7];
#pragma unroll
    for (int k = 0; k < 7; ++k) wt[k] = wtl[cl][k];
    __hip_bfloat16 o6[8];
#pragma unroll
    for (int u = 0; u < 8; ++u) {
      float acc = 0.f;
#pragma unroll
      for (int k = 0; k < 7; ++k) acc += wt[k] * hx[u + k];
      o6[u] = __float2bfloat16(acc);
    }
    *reinterpret_cast<bf16x8*>(&t6[((size_t)n * CD + c0 + cl) * SD + h * 64 + w8]) =
        *reinterpret_cast<const bf16x8*>(o6);
  }
}

// ---------------- GEMM B (4-phase/tile, 256x256 tile, BK=64) ----------------
// grid: (sb=16, 1, n=16) = 256 blocks, 512 threads (8 waves 2Mx4N, wave tile 128x64)
// LDS: 2 dbuf x (A 256x64 + B 256x64) bf16 = 128 KiB.
// Swizzle: physical 16B-granule = logical_granule ^ (row&7)  (both sides, rule 21).
// Choreography (round 6): ALL 8 stage-issues for tile kt+1 front-loaded into
// phase 0 (full-tile ~1000cyc slack before their single VMWAIT(0) at kt+1 ph0);
// 4 barriers/tile. Hazards: writes to buf[nxt] only after BAR_ph0 (postdates all
// reads of that buf from kt-1); reads of buf[cur] only after VMWAIT(0)+BAR_ph0.
#define STAGE_A(c, kt, d)                                                              \
  gload16(Ab + (size_t)((c) * 64 + wv * 8 + (lane >> 3)) * 2560 + (kt) * 128 + cbsrc,  \
          (char*)lds + (d) * 65536 + (c) * 8192 + wv * 1024)
#define STAGE_B(j, kt, d)                                                              \
  gload16(t2pb + (size_t)(s0 + (j) * 64 + wv * 8 + (lane >> 3) + 4 * (sb * 4 + (j))) * 512 + \
                     (kt) * 128 + cbsrc,                                               \
          (char*)lds + (d) * 65536 + 32768 + (j) * 8192 + wv * 1024)

#define LOAD_AV(d, MH)                                                                 \
  do {                                                                                 \
    const __hip_bfloat16* pA =                                                         \
        lds + (d) * 32768 + (wm * 128 + (MH) * 64 + l16) * 64;                         \
    _Pragma("unroll") for (int ks = 0; ks < 2; ++ks) {                                 \
      int cb = (ks * 32 + lg * 8) ^ lxor;                                              \
      _Pragma("unroll") for (int mf = 0; mf < 4; ++mf)                                 \
          av[ks * 4 + mf] = *reinterpret_cast<const bf16x8*>(pA + mf * 1024 + cb);     \
    }                                                                                  \
  } while (0)

#define QUADR(d, MH, NH)                                                               \
  do {                                                                                 \
    const __hip_bfloat16* pB =                                                         \
        lds + (d) * 32768 + 16384 + (wn * 64 + (NH) * 32 + l16) * 64;                  \
    bf16x8 bv[4];                                                                      \
    _Pragma("unroll") for (int ks = 0; ks < 2; ++ks) {                                 \
      int cb = (ks * 32 + lg * 8) ^ lxor;                                              \
      _Pragma("unroll") for (int nf = 0; nf < 2; ++nf)                                 \
          bv[ks * 2 + nf] = *reinterpret_cast<const bf16x8*>(pB + nf * 1024 + cb);     \
    }                                                                                  \
    __builtin_amdgcn_s_setprio(1);                                                     \
    _Pragma("unroll") for (int ks = 0; ks < 2; ++ks)                                   \
        _Pragma("unroll") for (int mf = 0; mf < 4; ++mf)                               \
            _Pragma("unroll") for (int nf = 0; nf < 2; ++nf)                           \
                acc[(MH) * 4 + mf][(NH) * 2 + nf] = __builtin_amdgcn_mfma_f32_16x16x32_bf16( \
                    av[ks * 4 + mf], bv[ks * 2 + nf], acc[(MH) * 4 + mf][(NH) * 2 + nf], \
                    0, 0, 0);                                                          \
    __builtin_amdgcn_s_setprio(0);                                                     \
  } while (0)

#define VMWAIT(N) asm volatile("s_waitcnt vmcnt(" #N ")" ::: "memory")
#define BARRIER() __builtin_amdgcn_s_barrier()

__global__ __launch_bounds__(512, 2) void gemm_b8(const __hip_bfloat16* __restrict__ A,
                                                  const __hip_bfloat16* __restrict__ t2p,
                                                  __hip_bfloat16* __restrict__ t3) {
  __shared__ __align__(16) __hip_bfloat16 lds[65536];  // 128 KiB
  const int n = blockIdx.z;
  const int sb = blockIdx.x;
  const int t = threadIdx.x;
  const int wv = t >> 6, lane = t & 63;
  const int wm = wv >> 2, wn = wv & 3;
  const int l16 = lane & 15, lg = lane >> 4;
  const int s0 = sb * 256;
  const char* Ab = (const char*)A;
  const char* t2pb = (const char*)(t2p + (size_t)n * HD * WP * CD);
  const int cbsrc = ((lane & 7) ^ (lane >> 3)) * 16;  // src-side swizzle (granule)
  const int lxor = (l16 & 7) * 8;                     // read-side row XOR (elems)

  f32x4 acc[8][4];
#pragma unroll
  for (int i = 0; i < 8; ++i)
#pragma unroll
    for (int j = 0; j < 4; ++j) acc[i][j] = (f32x4){0.f, 0.f, 0.f, 0.f};

  bf16x8 av[8];  // A fragments, reused across the NH-phase pair

  // prologue: stage kt=0 into buf 0
  STAGE_A(0, 0, 0); STAGE_A(2, 0, 0);
  STAGE_B(0, 0, 0); STAGE_B(1, 0, 0); STAGE_B(2, 0, 0); STAGE_B(3, 0, 0);
  STAGE_A(1, 0, 0); STAGE_A(3, 0, 0);

  for (int kt = 0; kt < 19; ++kt) {
    const int cur = kt & 1, nxt = cur ^ 1, kn = kt + 1;
    // phase 0: validate buf[cur] (only kt's 8 loads are outstanding), then
    // immediately front-load ALL of kt+1's stages into buf[nxt].
    VMWAIT(0);
    BARRIER();
    STAGE_A(0, kn, nxt); STAGE_A(2, kn, nxt);
    STAGE_B(0, kn, nxt); STAGE_B(1, kn, nxt); STAGE_B(2, kn, nxt); STAGE_B(3, kn, nxt);
    STAGE_A(1, kn, nxt); STAGE_A(3, kn, nxt);
    LOAD_AV(cur, 0);
    QUADR(cur, 0, 0);
    // phase 1: (0,1) — reuse av
    BARRIER();
    QUADR(cur, 0, 1);
    // phase 2: (1,0)
    BARRIER();
    LOAD_AV(cur, 1);
    QUADR(cur, 1, 0);
    // phase 3: (1,1) — reuse av
    BARRIER();
    QUADR(cur, 1, 1);
  }
  // peeled last tile kt=19 (buf 1): no staging, no further barriers needed
  VMWAIT(0);
  BARRIER();
  LOAD_AV(1, 0);
  QUADR(1, 0, 0);
  QUADR(1, 0, 1);
  LOAD_AV(1, 1);
  QUADR(1, 1, 0);
  QUADR(1, 1, 1);

  __hip_bfloat16* t3n = t3 + (size_t)n * CD * SD;
#pragma unroll
  for (int im = 0; im < 8; ++im)
#pragma unroll
    for (int in = 0; in < 4; ++in) {
      int row0 = wm * 128 + im * 16 + lg * 4;
      int col = s0 + wn * 64 + in * 16 + l16;
#pragma unroll
      for (int r = 0; r < 4; ++r)
        t3n[(size_t)(row0 + r) * SD + col] = __float2bfloat16(acc[im][in][r]);
    }
}

// ---------------- GEMM C (K-split x4): P4[kc][n][d][c] = sum_{s in chunk} t6*t3 ---------
__global__ __launch_bounds__(256) void gemm_c_part(const __hip_bfloat16* __restrict__ t6,
                                                   const __hip_bfloat16* __restrict__ t3,
                                                   float* __restrict__ P4) {
  __shared__ __align__(16) __hip_bfloat16 lA[64 * 64];
  __shared__ __align__(16) __hip_bfloat16 lB[64 * 64];
  int bx = blockIdx.x;
  int cbk = bx & 3, kc = bx >> 2;
  int db = blockIdx.y;
  int n = blockIdx.z;
  int t = threadIdx.x;
  int wave = t >> 6, lane = t & 63;
  int wm = wave >> 1, wn = wave & 1;
  int l16 = lane & 15, lg = lane >> 4;
  int d0 = db * 64;
  int c0 = cbk * 64;
  int kbase = kc * 1024;
  const __hip_bfloat16* An = t6 + (size_t)n * CD * SD + kbase;
  const __hip_bfloat16* Bn = t3 + (size_t)n * CD * SD + kbase;

  int srow = t >> 3;
  int scol = (t & 7) * 8;
  const __hip_bfloat16* gA0 = An + (size_t)(d0 + srow) * SD + scol;
  const __hip_bfloat16* gA1 = An + (size_t)(d0 + srow + 32) * SD + scol;
  const __hip_bfloat16* gB0 = Bn + (size_t)(c0 + srow) * SD + scol;
  const __hip_bfloat16* gB1 = Bn + (size_t)(c0 + srow + 32) * SD + scol;
  __hip_bfloat16* lAd0 = &lA[t * 8];
  __hip_bfloat16* lAd1 = &lA[t * 8 + 32 * 64];
  __hip_bfloat16* lBd0 = &lB[t * 8];
  __hip_bfloat16* lBd1 = &lB[t * 8 + 32 * 64];

  f32x4 acc[2][2];
#pragma unroll
  for (int mi = 0; mi < 2; ++mi)
#pragma unroll
    for (int ni = 0; ni < 2; ++ni) acc[mi][ni] = (f32x4){0.f, 0.f, 0.f, 0.f};

  gload16(gA0, lAd0);
  gload16(gA1, lAd1);
  gload16(gB0, lBd0);
  gload16(gB1, lBd1);

  for (int k = 0; k < 16; ++k) {
    __syncthreads();
#pragma unroll
    for (int ks = 0; ks < 2; ++ks) {
      bf16x8 a[2], b[2];
#pragma unroll
      for (int mi = 0; mi < 2; ++mi)
        a[mi] = *reinterpret_cast<const bf16x8*>(&lA[(wm * 32 + mi * 16 + l16) * 64 + ks * 32 + lg * 8]);
#pragma unroll
      for (int ni = 0; ni < 2; ++ni)
        b[ni] = *reinterpret_cast<const bf16x8*>(&lB[(wn * 32 + ni * 16 + l16) * 64 + ks * 32 + lg * 8]);
#pragma unroll
      for (int mi = 0; mi < 2; ++mi)
#pragma unroll
        for (int ni = 0; ni < 2; ++ni)
          acc[mi][ni] = __builtin_amdgcn_mfma_f32_16x16x32_bf16(a[mi], b[ni], acc[mi][ni], 0, 0, 0);
    }
    __syncthreads();
    if (k < 15) {
      int kk = (k + 1) * 64;
      gload16(gA0 + kk, lAd0);
      gload16(gA1 + kk, lAd1);
      gload16(gB0 + kk, lBd0);
      gload16(gB1 + kk, lBd1);
    }
  }

  float* Pn = P4 + ((size_t)kc * NB + n) * CD * CD;
#pragma unroll
  for (int mi = 0; mi < 2; ++mi)
#pragma unroll
    for (int ni = 0; ni < 2; ++ni) {
      int col = c0 + wn * 32 + ni * 16 + l16;
      int row0 = d0 + wm * 32 + mi * 16 + lg * 4;
#pragma unroll
      for (int r = 0; r < 4; ++r)
        Pn[(size_t)(row0 + r) * CD + col] = acc[mi][ni][r];
    }
}

// ---------------- reduce P4 -> P (bf16, x 1/64) ----------------
__global__ __launch_bounds__(256) void reduce_P(const float* __restrict__ P4,
                                                __hip_bfloat16* __restrict__ P) {
  size_t i = ((size_t)blockIdx.x * 256 + threadIdx.x) * 4;
  const size_t stride = (size_t)NB * CD * CD;
  float4 a = *reinterpret_cast<const float4*>(P4 + i);
  float4 b = *reinterpret_cast<const float4*>(P4 + stride + i);
  float4 c = *reinterpret_cast<const float4*>(P4 + 2 * stride + i);
  float4 d = *reinterpret_cast<const float4*>(P4 + 3 * stride + i);
  __hip_bfloat16 o[4];
  o[0] = __float2bfloat16((a.x + b.x + c.x + d.x) * 0.015625f);
  o[1] = __float2bfloat16((a.y + b.y + c.y + d.y) * 0.015625f);
  o[2] = __float2bfloat16((a.z + b.z + c.z + d.z) * 0.015625f);
  o[3] = __float2bfloat16((a.w + b.w + c.w + d.w) * 0.015625f);
  *reinterpret_cast<short4*>(&P[i]) = *reinterpret_cast<const short4*>(o);
}

// ---------------- GEMM D: out[n][d][s] = (1/16) * sum_c P[n][d][c] * t5T[n][s][c] -------
__global__ __launch_bounds__(256) void gemm_d(const __hip_bfloat16* __restrict__ P,
                                              const __hip_bfloat16* __restrict__ t5T,
                                              float* __restrict__ out) {
  __shared__ __align__(16) __hip_bfloat16 lA[128 * 32];
  __shared__ __align__(16) __hip_bfloat16 lB[128 * 32];
  int n = blockIdx.z;
  int db = blockIdx.y;
  int sb = blockIdx.x;
  int t = threadIdx.x;
  int wave = t >> 6, lane = t & 63;
  int wm = wave >> 1, wn = wave & 1;
  int l16 = lane & 15, lg = lane >> 4;
  int d0 = db * 128;
  int s0 = sb * 128;
  const __hip_bfloat16* An = P + (size_t)n * CD * CD;
  const __hip_bfloat16* Bn = t5T + (size_t)n * SD * CD;

  int srow = t >> 2;
  int scol = (t & 3) * 8;
  const __hip_bfloat16* gA0 = An + (size_t)(d0 + srow) * CD + scol;
  const __hip_bfloat16* gA1 = An + (size_t)(d0 + srow + 64) * CD + scol;
  const __hip_bfloat16* gB0 = Bn + (size_t)(s0 + srow) * CD + scol;
  const __hip_bfloat16* gB1 = Bn + (size_t)(s0 + srow + 64) * CD + scol;
  __hip_bfloat16* lAd0 = &lA[t * 8];
  __hip_bfloat16* lAd1 = &lA[t * 8 + 64 * 32];
  __hip_bfloat16* lBd0 = &lB[t * 8];
  __hip_bfloat16* lBd1 = &lB[t * 8 + 64 * 32];

  f32x4 acc[4][4];
#pragma unroll
  for (int mi = 0; mi < 4; ++mi)
#pragma unroll
    for (int ni = 0; ni < 4; ++ni) acc[mi][ni] = (f32x4){0.f, 0.f, 0.f, 0.f};

  gload16(gA0, lAd0);
  gload16(gA1, lAd1);
  gload16(gB0, lBd0);
  gload16(gB1, lBd1);

  for (int k = 0; k < 8; ++k) {
    __syncthreads();
    bf16x8 a[4], b[4];
#pragma unroll
    for (int mi = 0; mi < 4; ++mi)
      a[mi] = *reinterpret_cast<const bf16x8*>(&lA[(wm * 64 + mi * 16 + l16) * 32 + lg * 8]);
#pragma unroll
    for (int ni = 0; ni < 4; ++ni)
      b[ni] = *reinterpret_cast<const bf16x8*>(&lB[(wn * 64 + ni * 16 + l16) * 32 + lg * 8]);
#pragma unroll
    for (int mi = 0; mi < 4; ++mi)
#pragma unroll
      for (int ni = 0; ni < 4; ++ni)
        acc[mi][ni] = __builtin_amdgcn_mfma_f32_16x16x32_bf16(a[mi], b[ni], acc[mi][ni], 0, 0, 0);
    __syncthreads();
    if (k < 7) {
      int kk = (k + 1) * 32;
      gload16(gA0 + kk, lAd0);
      gload16(gA1 + kk, lAd1);
      gload16(gB0 + kk, lBd0);
      gload16(gB1 + kk, lBd1);
    }
  }

  float* outn = out + (size_t)n * CD * SD;
#pragma unroll
  for (int mi = 0; mi < 4; ++mi)
#pragma unroll
    for (int ni = 0; ni < 4; ++ni) {
      int col = s0 + wn * 64 + ni * 16 + l16;
      int row0 = d0 + wm * 64 + mi * 16 + lg * 4;
#pragma unroll
      for (int r = 0; r < 4; ++r)
        outn[(size_t)(row0 + r) * SD + col] = acc[mi][ni][r] * 0.0625f;
    }
}

extern "C" void kernel_launch(void* const* d_in, const int* in_sizes, int n_in,
                              void* d_out, int out_size, void* d_ws, size_t ws_size,
                              hipStream_t stream) {
  const float* x = (const float*)d_in[0];
  const float* p2 = (const float*)d_in[1];
  const float* p3 = (const float*)d_in[2];
  const float* p4 = (const float*)d_in[3];
  const float* p6 = (const float*)d_in[4];

  char* ws = (char*)d_ws;
  size_t off = 0;
  __hip_bfloat16* A = (__hip_bfloat16*)(ws + off);
  off += (size_t)CD * KU * 2;                       // 640 KiB
  size_t t2p_off = off;
  __hip_bfloat16* t2p = (__hip_bfloat16*)(ws + off);
  off += (size_t)NB * HD * WP * CD * 2;             // ~35.7 MiB
  __hip_bfloat16* t5T = (__hip_bfloat16*)(ws + off);
  off += (size_t)NB * SD * CD * 2;                  // 32 MiB
  __hip_bfloat16* t6 = (__hip_bfloat16*)(ws + off);
  off += (size_t)NB * CD * SD * 2;                  // 32 MiB
  __hip_bfloat16* t3 = (__hip_bfloat16*)(ws + off);
  off += (size_t)NB * CD * SD * 2;                  // 32 MiB
  float* P4 = (float*)(ws + t2p_off);
  __hip_bfloat16* P = (__hip_bfloat16*)(ws + t2p_off + (size_t)4 * NB * CD * CD * 4);

  float* out = (float*)d_out;

  prep_w3<<<dim3((CD * KU + 255) / 256), 256, 0, stream>>>(p3, A);
  prep_x<<<dim3(HD, 4, NB), 256, 0, stream>>>(x, p2, p4, p6, t2p, t5T, t6);
  gemm_b8<<<dim3(16, 1, NB), 512, 0, stream>>>(A, t2p, t3);
  gemm_c_part<<<dim3(16, 4, NB), 256, 0, stream>>>(t6, t3, P4);
  reduce_P<<<dim3((NB * CD * CD / 4) / 256), 256, 0, stream>>>(P4, P);
  gemm_d<<<dim3(32, 2, NB), 256, 0, stream>>>(P, t5T, out);
}

// Round 8
// 133.263 us; speedup vs baseline: 1.0365x; 1.0365x over previous
//
#include <hip/hip_runtime.h>
#include <hip/hip_bf16.h>

typedef __attribute__((ext_vector_type(8))) short bf16x8;
typedef __attribute__((ext_vector_type(4))) float f32x4;

#define NB 16
#define CD 256
#define HD 64
#define WD 64
#define WP 68   // padded width
#define SD 4096
#define KU 1280  // 5 * 256

__device__ __forceinline__ void gload16(const void* g, void* lds) {
  __builtin_amdgcn_global_load_lds(
      (const __attribute__((address_space(1))) unsigned int*)g,
      (__attribute__((address_space(3))) unsigned int*)lds, 16, 0, 0);
}

// ---------------- prep W3: A[o][j*256+c] = p3[o,c,0,j] (bf16) ----------------
__global__ __launch_bounds__(256) void prep_w3(const float* __restrict__ p3,
                                               __hip_bfloat16* __restrict__ A) {
  int id = blockIdx.x * 256 + threadIdx.x;
  if (id >= CD * KU) return;
  int o = id / KU;
  int r = id - o * KU;
  int j = r >> 8;
  int c = r & 255;
  A[id] = __float2bfloat16(p3[(o * CD + c) * 5 + j]);
}

// ---------------- prep X: t2p [N][H][WP][C] (zero-padded), t5T [N][S][C], t6 [N][C][S] ---
__global__ __launch_bounds__(256) void prep_x(const float* __restrict__ x,
                                              const float* __restrict__ p2,
                                              const float* __restrict__ p4,
                                              const float* __restrict__ p6,
                                              __hip_bfloat16* __restrict__ t2p,
                                              __hip_bfloat16* __restrict__ t5T,
                                              __hip_bfloat16* __restrict__ t6) {
  int h = blockIdx.x;
  int c0 = blockIdx.y * 64;
  int n = blockIdx.z;
  __shared__ float xl[64][67];
  __shared__ float p2l[64];
  __shared__ float wtl[64][8];
  int t = threadIdx.x;

  if (t < 64) p2l[t] = p2[(c0 + t) * HD + h];
  for (int idx = t; idx < 448; idx += 256) {
    int c = idx / 7, k = idx - c * 7;
    wtl[c][k] = p4[(c0 + c) * 7 + k] * p6[k];
  }

  {
    int cq = t >> 4;
    int w4 = (t & 15) * 4;
#pragma unroll
    for (int cc = 0; cc < 4; ++cc) {
      int cl = cc * 16 + cq;
      const float4 xv = *reinterpret_cast<const float4*>(
          &x[(((size_t)n * CD + c0 + cl) * HD + h) * WD + w4]);
      xl[cl][w4 + 0] = xv.x;
      xl[cl][w4 + 1] = xv.y;
      xl[cl][w4 + 2] = xv.z;
      xl[cl][w4 + 3] = xv.w;
    }
  }
  __syncthreads();

  __hip_bfloat16* t2pn = t2p + (size_t)n * HD * WP * CD;
#pragma unroll
  for (int ii = 0; ii < 2; ++ii) {
    int w = (t >> 3) + ii * 32;
    int cb = (t & 7) * 8;
    __hip_bfloat16 o2[8], o5[8];
#pragma unroll
    for (int j = 0; j < 8; ++j) {
      float xv = xl[cb + j][w];
      o5[j] = __float2bfloat16(fmaxf(xv, 0.f));
      o2[j] = __float2bfloat16(p2l[cb + j] * xv);
    }
    size_t s = (size_t)h * 64 + w;
    *reinterpret_cast<bf16x8*>(&t5T[((size_t)n * SD + s) * CD + c0 + cb]) =
        *reinterpret_cast<const bf16x8*>(o5);
    *reinterpret_cast<bf16x8*>(&t2pn[((size_t)h * WP + w + 2) * CD + c0 + cb]) =
        *reinterpret_cast<const bf16x8*>(o2);
  }
  if (t < 32) {
    int pi = t >> 3;
    int wp = (pi < 2) ? pi : pi + 64;
    int cb = (t & 7) * 8;
    bf16x8 z = (bf16x8){0, 0, 0, 0, 0, 0, 0, 0};
    *reinterpret_cast<bf16x8*>(&t2pn[((size_t)h * WP + wp) * CD + c0 + cb]) = z;
  }

#pragma unroll
  for (int ii = 0; ii < 2; ++ii) {
    int cl = (t >> 3) + ii * 32;
    int w8 = (t & 7) * 8;
    float hx[14];
#pragma unroll
    for (int m = 0; m < 14; ++m) {
      int wi = w8 - 3 + m;
      hx[m] = (wi >= 0 && wi < 64) ? xl[cl][wi] : 0.f;
    }
    float wt[7];
#pragma unroll
    for (int k = 0; k < 7; ++k) wt[k] = wtl[cl][k];
    __hip_bfloat16 o6[8];
#pragma unroll
    for (int u = 0; u < 8; ++u) {
      float acc = 0.f;
#pragma unroll
      for (int k = 0; k < 7; ++k) acc += wt[k] * hx[u + k];
      o6[u] = __float2bfloat16(acc);
    }
    *reinterpret_cast<bf16x8*>(&t6[((size_t)n * CD + c0 + cl) * SD + h * 64 + w8]) =
        *reinterpret_cast<const bf16x8*>(o6);
  }
}

// ---------------- GEMM B (8-phase, 256x256 tile, BK=64, counted vmcnt) ----------------
// grid: (sb=16, 1, n=16) = 256 blocks, 512 threads (8 waves 2Mx4N, wave tile 128x64)
// Round-5 choreography (best measured): stages spread 2/phase, VMWAIT(4)@ph0,
// VMWAIT(6)@ph2, 8 barriers/tile. Swizzle: granule ^= row&7 both sides.
#define STAGE_A(c, kt, d)                                                              \
  gload16(Ab + (size_t)((c) * 64 + wv * 8 + (lane >> 3)) * 2560 + (kt) * 128 + cbsrc,  \
          (char*)lds + (d) * 65536 + (c) * 8192 + wv * 1024)
#define STAGE_B(j, kt, d)                                                              \
  gload16(t2pb + (size_t)(s0 + (j) * 64 + wv * 8 + (lane >> 3) + 4 * (sb * 4 + (j))) * 512 + \
                     (kt) * 128 + cbsrc,                                               \
          (char*)lds + (d) * 65536 + 32768 + (j) * 8192 + wv * 1024)

#define LOAD_AV(d, MH)                                                                 \
  do {                                                                                 \
    const __hip_bfloat16* pA =                                                         \
        lds + (d) * 32768 + (wm * 128 + (MH) * 64 + l16) * 64;                         \
    _Pragma("unroll") for (int ks = 0; ks < 2; ++ks) {                                 \
      int cb = (ks * 32 + lg * 8) ^ lxor;                                              \
      _Pragma("unroll") for (int mf = 0; mf < 4; ++mf)                                 \
          av[ks * 4 + mf] = *reinterpret_cast<const bf16x8*>(pA + mf * 1024 + cb);     \
    }                                                                                  \
  } while (0)

#define QUADR(d, MH, NH)                                                               \
  do {                                                                                 \
    const __hip_bfloat16* pB =                                                         \
        lds + (d) * 32768 + 16384 + (wn * 64 + (NH) * 32 + l16) * 64;                  \
    bf16x8 bv[4];                                                                      \
    _Pragma("unroll") for (int ks = 0; ks < 2; ++ks) {                                 \
      int cb = (ks * 32 + lg * 8) ^ lxor;                                              \
      _Pragma("unroll") for (int nf = 0; nf < 2; ++nf)                                 \
          bv[ks * 2 + nf] = *reinterpret_cast<const bf16x8*>(pB + nf * 1024 + cb);     \
    }                                                                                  \
    __builtin_amdgcn_s_setprio(1);                                                     \
    _Pragma("unroll") for (int ks = 0; ks < 2; ++ks)                                   \
        _Pragma("unroll") for (int mf = 0; mf < 4; ++mf)                               \
            _Pragma("unroll") for (int nf = 0; nf < 2; ++nf)                           \
                acc[(MH) * 4 + mf][(NH) * 2 + nf] = __builtin_amdgcn_mfma_f32_16x16x32_bf16( \
                    av[ks * 4 + mf], bv[ks * 2 + nf], acc[(MH) * 4 + mf][(NH) * 2 + nf], \
                    0, 0, 0);                                                          \
    __builtin_amdgcn_s_setprio(0);                                                     \
  } while (0)

#define VMWAIT(N) asm volatile("s_waitcnt vmcnt(" #N ")" ::: "memory")
#define BARRIER() __builtin_amdgcn_s_barrier()

__global__ __launch_bounds__(512, 2) void gemm_b8(const __hip_bfloat16* __restrict__ A,
                                                  const __hip_bfloat16* __restrict__ t2p,
                                                  __hip_bfloat16* __restrict__ t3) {
  __shared__ __align__(16) __hip_bfloat16 lds[65536];  // 128 KiB
  const int n = blockIdx.z;
  const int sb = blockIdx.x;
  const int t = threadIdx.x;
  const int wv = t >> 6, lane = t & 63;
  const int wm = wv >> 2, wn = wv & 3;
  const int l16 = lane & 15, lg = lane >> 4;
  const int s0 = sb * 256;
  const char* Ab = (const char*)A;
  const char* t2pb = (const char*)(t2p + (size_t)n * HD * WP * CD);
  const int cbsrc = ((lane & 7) ^ (lane >> 3)) * 16;  // src-side swizzle (granule)
  const int lxor = (l16 & 7) * 8;                     // read-side row XOR (elems)

  f32x4 acc[8][4];
#pragma unroll
  for (int i = 0; i < 8; ++i)
#pragma unroll
    for (int j = 0; j < 4; ++j) acc[i][j] = (f32x4){0.f, 0.f, 0.f, 0.f};

  bf16x8 av[8];  // A fragments, reused across the NH-phase pair

  // prologue: stage kt=0 into buf 0 in consumption order
  STAGE_B(0, 0, 0); STAGE_B(1, 0, 0); STAGE_B(2, 0, 0); STAGE_B(3, 0, 0);
  STAGE_A(0, 0, 0); STAGE_A(2, 0, 0); STAGE_A(1, 0, 0); STAGE_A(3, 0, 0);

  for (int kt = 0; kt < 19; ++kt) {
    const int cur = kt & 1, nxt = cur ^ 1, kn = kt + 1;
    // phase 0: quadrant (mh=0, nh=0)
    STAGE_B(0, kn, nxt); STAGE_B(1, kn, nxt);
    VMWAIT(4);
    BARRIER();
    LOAD_AV(cur, 0);
    QUADR(cur, 0, 0);
    BARRIER();
    // phase 1: (0,1) — reuse av
    STAGE_B(2, kn, nxt); STAGE_B(3, kn, nxt);
    BARRIER();
    QUADR(cur, 0, 1);
    BARRIER();
    // phase 2: (1,0)
    STAGE_A(0, kn, nxt); STAGE_A(2, kn, nxt);
    VMWAIT(6);
    BARRIER();
    LOAD_AV(cur, 1);
    QUADR(cur, 1, 0);
    BARRIER();
    // phase 3: (1,1) — reuse av
    STAGE_A(1, kn, nxt); STAGE_A(3, kn, nxt);
    BARRIER();
    QUADR(cur, 1, 1);
    BARRIER();
  }
  // peeled last tile kt=19 (buf 1): epilogue drain 2 -> 0
  VMWAIT(2);
  BARRIER();
  LOAD_AV(1, 0);
  QUADR(1, 0, 0);
  BARRIER();
  BARRIER();
  QUADR(1, 0, 1);
  BARRIER();
  VMWAIT(0);
  BARRIER();
  LOAD_AV(1, 1);
  QUADR(1, 1, 0);
  BARRIER();
  BARRIER();
  QUADR(1, 1, 1);
  BARRIER();

  __hip_bfloat16* t3n = t3 + (size_t)n * CD * SD;
#pragma unroll
  for (int im = 0; im < 8; ++im)
#pragma unroll
    for (int in = 0; in < 4; ++in) {
      int row0 = wm * 128 + im * 16 + lg * 4;
      int col = s0 + wn * 64 + in * 16 + l16;
#pragma unroll
      for (int r = 0; r < 4; ++r)
        t3n[(size_t)(row0 + r) * SD + col] = __float2bfloat16(acc[im][in][r]);
    }
}

// ---------------- GEMM C (K-split x4): P4[kc][n][d][c] = sum_{s in chunk} t6*t3 ---------
__global__ __launch_bounds__(256) void gemm_c_part(const __hip_bfloat16* __restrict__ t6,
                                                   const __hip_bfloat16* __restrict__ t3,
                                                   float* __restrict__ P4) {
  __shared__ __align__(16) __hip_bfloat16 lA[64 * 64];
  __shared__ __align__(16) __hip_bfloat16 lB[64 * 64];
  int bx = blockIdx.x;
  int cbk = bx & 3, kc = bx >> 2;
  int db = blockIdx.y;
  int n = blockIdx.z;
  int t = threadIdx.x;
  int wave = t >> 6, lane = t & 63;
  int wm = wave >> 1, wn = wave & 1;
  int l16 = lane & 15, lg = lane >> 4;
  int d0 = db * 64;
  int c0 = cbk * 64;
  int kbase = kc * 1024;
  const __hip_bfloat16* An = t6 + (size_t)n * CD * SD + kbase;
  const __hip_bfloat16* Bn = t3 + (size_t)n * CD * SD + kbase;

  int srow = t >> 3;
  int scol = (t & 7) * 8;
  const __hip_bfloat16* gA0 = An + (size_t)(d0 + srow) * SD + scol;
  const __hip_bfloat16* gA1 = An + (size_t)(d0 + srow + 32) * SD + scol;
  const __hip_bfloat16* gB0 = Bn + (size_t)(c0 + srow) * SD + scol;
  const __hip_bfloat16* gB1 = Bn + (size_t)(c0 + srow + 32) * SD + scol;
  __hip_bfloat16* lAd0 = &lA[t * 8];
  __hip_bfloat16* lAd1 = &lA[t * 8 + 32 * 64];
  __hip_bfloat16* lBd0 = &lB[t * 8];
  __hip_bfloat16* lBd1 = &lB[t * 8 + 32 * 64];

  f32x4 acc[2][2];
#pragma unroll
  for (int mi = 0; mi < 2; ++mi)
#pragma unroll
    for (int ni = 0; ni < 2; ++ni) acc[mi][ni] = (f32x4){0.f, 0.f, 0.f, 0.f};

  gload16(gA0, lAd0);
  gload16(gA1, lAd1);
  gload16(gB0, lBd0);
  gload16(gB1, lBd1);

  for (int k = 0; k < 16; ++k) {
    __syncthreads();
#pragma unroll
    for (int ks = 0; ks < 2; ++ks) {
      bf16x8 a[2], b[2];
#pragma unroll
      for (int mi = 0; mi < 2; ++mi)
        a[mi] = *reinterpret_cast<const bf16x8*>(&lA[(wm * 32 + mi * 16 + l16) * 64 + ks * 32 + lg * 8]);
#pragma unroll
      for (int ni = 0; ni < 2; ++ni)
        b[ni] = *reinterpret_cast<const bf16x8*>(&lB[(wn * 32 + ni * 16 + l16) * 64 + ks * 32 + lg * 8]);
#pragma unroll
      for (int mi = 0; mi < 2; ++mi)
#pragma unroll
        for (int ni = 0; ni < 2; ++ni)
          acc[mi][ni] = __builtin_amdgcn_mfma_f32_16x16x32_bf16(a[mi], b[ni], acc[mi][ni], 0, 0, 0);
    }
    __syncthreads();
    if (k < 15) {
      int kk = (k + 1) * 64;
      gload16(gA0 + kk, lAd0);
      gload16(gA1 + kk, lAd1);
      gload16(gB0 + kk, lBd0);
      gload16(gB1 + kk, lBd1);
    }
  }

  float* Pn = P4 + ((size_t)kc * NB + n) * CD * CD;
#pragma unroll
  for (int mi = 0; mi < 2; ++mi)
#pragma unroll
    for (int ni = 0; ni < 2; ++ni) {
      int col = c0 + wn * 32 + ni * 16 + l16;
      int row0 = d0 + wm * 32 + mi * 16 + lg * 4;
#pragma unroll
      for (int r = 0; r < 4; ++r)
        Pn[(size_t)(row0 + r) * CD + col] = acc[mi][ni][r];
    }
}

// ---------------- reduce P4 -> P (bf16, x 1/64) ----------------
__global__ __launch_bounds__(256) void reduce_P(const float* __restrict__ P4,
                                                __hip_bfloat16* __restrict__ P) {
  size_t i = ((size_t)blockIdx.x * 256 + threadIdx.x) * 4;
  const size_t stride = (size_t)NB * CD * CD;
  float4 a = *reinterpret_cast<const float4*>(P4 + i);
  float4 b = *reinterpret_cast<const float4*>(P4 + stride + i);
  float4 c = *reinterpret_cast<const float4*>(P4 + 2 * stride + i);
  float4 d = *reinterpret_cast<const float4*>(P4 + 3 * stride + i);
  __hip_bfloat16 o[4];
  o[0] = __float2bfloat16((a.x + b.x + c.x + d.x) * 0.015625f);
  o[1] = __float2bfloat16((a.y + b.y + c.y + d.y) * 0.015625f);
  o[2] = __float2bfloat16((a.z + b.z + c.z + d.z) * 0.015625f);
  o[3] = __float2bfloat16((a.w + b.w + c.w + d.w) * 0.015625f);
  *reinterpret_cast<short4*>(&P[i]) = *reinterpret_cast<const short4*>(o);
}

// ---------------- GEMM D: out[n][d][s] = (1/16) * sum_c P[n][d][c] * t5T[n][s][c] -------
// NEW: tile 256(d, full)x128(s), BK=64, grid (32,1,16)=512 blocks = 2/CU.
// 256 threads, 4 waves 2Mx2N, wave tile 128x64. Single-buffer 2-barrier loop, 4 iters.
// LDS 48 KB; swizzle: granule ^= row&7 both sides (proven gemm_b8 scheme, 128B rows).
#define DSTAGE_A(i, kk)                                                                \
  gload16(Pb + (size_t)((i) * 32 + wv4 * 8 + (lane >> 3)) * 512 + (kk) * 128 + cbsrc,  \
          (char*)lA + (i) * 4096 + wv4 * 1024)
#define DSTAGE_B(i, kk)                                                                \
  gload16(Tb + (size_t)(s0 + (i) * 32 + wv4 * 8 + (lane >> 3)) * 512 + (kk) * 128 + cbsrc, \
          (char*)lB + (i) * 4096 + wv4 * 1024)

__global__ __launch_bounds__(256, 2) void gemm_d(const __hip_bfloat16* __restrict__ P,
                                                 const __hip_bfloat16* __restrict__ t5T,
                                                 float* __restrict__ out) {
  __shared__ __align__(16) __hip_bfloat16 lA[256 * 64];  // 32 KB
  __shared__ __align__(16) __hip_bfloat16 lB[128 * 64];  // 16 KB
  const int n = blockIdx.z;
  const int sb = blockIdx.x;
  const int t = threadIdx.x;
  const int wv4 = t >> 6, lane = t & 63;
  const int wm = wv4 >> 1, wn = wv4 & 1;
  const int l16 = lane & 15, lg = lane >> 4;
  const int s0 = sb * 128;
  const char* Pb = (const char*)(P + (size_t)n * CD * CD);
  const char* Tb = (const char*)(t5T + (size_t)n * SD * CD);
  const int cbsrc = ((lane & 7) ^ (lane >> 3)) * 16;
  const int lxor = (l16 & 7) * 8;

  f32x4 acc[8][4];
#pragma unroll
  for (int i = 0; i < 8; ++i)
#pragma unroll
    for (int j = 0; j < 4; ++j) acc[i][j] = (f32x4){0.f, 0.f, 0.f, 0.f};

  // stage k=0 (A: 8 calls, B: 4 calls)
#pragma unroll
  for (int i = 0; i < 8; ++i) DSTAGE_A(i, 0);
#pragma unroll
  for (int i = 0; i < 4; ++i) DSTAGE_B(i, 0);

  for (int k = 0; k < 4; ++k) {
    __syncthreads();  // drains vmcnt: staging visible
#pragma unroll
    for (int ks = 0; ks < 2; ++ks) {
      int cb = (ks * 32 + lg * 8) ^ lxor;
      bf16x8 a[8], b[4];
#pragma unroll
      for (int mf = 0; mf < 8; ++mf)
        a[mf] = *reinterpret_cast<const bf16x8*>(&lA[(wm * 128 + mf * 16 + l16) * 64 + cb]);
#pragma unroll
      for (int nf = 0; nf < 4; ++nf)
        b[nf] = *reinterpret_cast<const bf16x8*>(&lB[(wn * 64 + nf * 16 + l16) * 64 + cb]);
#pragma unroll
      for (int mf = 0; mf < 8; ++mf)
#pragma unroll
        for (int nf = 0; nf < 4; ++nf)
          acc[mf][nf] = __builtin_amdgcn_mfma_f32_16x16x32_bf16(a[mf], b[nf], acc[mf][nf], 0, 0, 0);
    }
    __syncthreads();  // all waves done reading before overwrite
    if (k < 3) {
      int kk = k + 1;
#pragma unroll
      for (int i = 0; i < 8; ++i) DSTAGE_A(i, kk);
#pragma unroll
      for (int i = 0; i < 4; ++i) DSTAGE_B(i, kk);
    }
  }

  float* outn = out + (size_t)n * CD * SD;
#pragma unroll
  for (int mf = 0; mf < 8; ++mf)
#pragma unroll
    for (int nf = 0; nf < 4; ++nf) {
      int col = s0 + wn * 64 + nf * 16 + l16;
      int row0 = wm * 128 + mf * 16 + lg * 4;
#pragma unroll
      for (int r = 0; r < 4; ++r)
        outn[(size_t)(row0 + r) * SD + col] = acc[mf][nf][r] * 0.0625f;
    }
}

extern "C" void kernel_launch(void* const* d_in, const int* in_sizes, int n_in,
                              void* d_out, int out_size, void* d_ws, size_t ws_size,
                              hipStream_t stream) {
  const float* x = (const float*)d_in[0];
  const float* p2 = (const float*)d_in[1];
  const float* p3 = (const float*)d_in[2];
  const float* p4 = (const float*)d_in[3];
  const float* p6 = (const float*)d_in[4];

  char* ws = (char*)d_ws;
  size_t off = 0;
  __hip_bfloat16* A = (__hip_bfloat16*)(ws + off);
  off += (size_t)CD * KU * 2;                       // 640 KiB
  size_t t2p_off = off;
  __hip_bfloat16* t2p = (__hip_bfloat16*)(ws + off);
  off += (size_t)NB * HD * WP * CD * 2;             // ~35.7 MiB
  __hip_bfloat16* t5T = (__hip_bfloat16*)(ws + off);
  off += (size_t)NB * SD * CD * 2;                  // 32 MiB
  __hip_bfloat16* t6 = (__hip_bfloat16*)(ws + off);
  off += (size_t)NB * CD * SD * 2;                  // 32 MiB
  __hip_bfloat16* t3 = (__hip_bfloat16*)(ws + off);
  off += (size_t)NB * CD * SD * 2;                  // 32 MiB
  float* P4 = (float*)(ws + t2p_off);
  __hip_bfloat16* P = (__hip_bfloat16*)(ws + t2p_off + (size_t)4 * NB * CD * CD * 4);

  float* out = (float*)d_out;

  prep_w3<<<dim3((CD * KU + 255) / 256), 256, 0, stream>>>(p3, A);
  prep_x<<<dim3(HD, 4, NB), 256, 0, stream>>>(x, p2, p4, p6, t2p, t5T, t6);
  gemm_b8<<<dim3(16, 1, NB), 512, 0, stream>>>(A, t2p, t3);
  gemm_c_part<<<dim3(16, 4, NB), 256, 0, stream>>>(t6, t3, P4);
  reduce_P<<<dim3((NB * CD * CD / 4) / 256), 256, 0, stream>>>(P4, P);
  gemm_d<<<dim3(32, 1, NB), 256, 0, stream>>>(P, t5T, out);
}